// Round 18
// baseline (129.148 us; speedup 1.0000x reference)
//
#include <hip/hip_runtime.h>
#include <hip/hip_bf16.h>

typedef __hip_bfloat16 bf16;
typedef __attribute__((ext_vector_type(8))) short bf16x8;
typedef __attribute__((ext_vector_type(4))) float f32x4;

#define BDIM 4
#define CDIM 512
#define NHEADS 8
#define NGROUPS 4
#define GCH 128

__device__ __forceinline__ float bf2f(bf16 v) { return __bfloat162float(v); }
__device__ __forceinline__ float bfu2f(unsigned short u) {
  return __uint_as_float(((unsigned)u) << 16);
}
__device__ __forceinline__ unsigned short f2bu(float v) {
  return __hip_bfloat16_raw(__float2bfloat16(v)).x;
}
__device__ __forceinline__ unsigned pack2(float lo, float hi) {
  return (unsigned)f2bu(lo) | ((unsigned)f2bu(hi) << 16);
}

// ---- MFMA GEMM, 32x64 tile: out_m[b][o][n] = sum_c Wm[o][c]*in[b][c][n]+bias.
// Grid (16 n, 16 o, 4 b) = 1024 blocks = 4 independent blocks/CU (separate
// barrier groups -> true TLP; r17's in-block split-K was lockstep and lost).
// 256 thr = 4 waves, wave w owns 16x32 quadrant: o_base=(w>>1)*16,
// n_base=(w&1)*32. Full K per block -> summation order identical to r15.
template <bool IN_F32, typename OutT, int NMAT>
__global__ __launch_bounds__(256) void gemm_kernel(
    const float* __restrict__ W0, const float* __restrict__ bias0,
    const float* __restrict__ W1, const float* __restrict__ bias1,
    const void* __restrict__ in,
    OutT* __restrict__ out0, OutT* __restrict__ out1) {
  __shared__ __align__(16) unsigned char smem[4096 * NMAT + 8192];
  unsigned char* b_lds = smem + 4096 * NMAT;  // [64 n][64 c] bf16 swz
  const int b = blockIdx.z;
  const int o0 = blockIdx.y * 32;
  const int n0 = blockIdx.x * 64;
  const int t = threadIdx.x, l = t & 63, w = t >> 6;
  const int rg = l >> 4, cl = l & 15;
  const int o_base = (w >> 1) * 16, n_base = (w & 1) * 32;
  const int ar = t >> 3;         // A stage: row 0..31
  const int ac8 = (t & 7) * 8;   // A stage: col block
  const int kc2 = (t & 31) * 2;  // B stage: channel pair
  const int kn8 = (t >> 5) * 8;  // B stage: n block
  const unsigned swa = (unsigned)((ar & 7) << 4);
  const float* Ws[2] = {W0, W1};
  const float* Bs[2] = {bias0, bias1};
  OutT* Os[2] = {out0, out1};

  f32x4 acc[NMAT][2];
#pragma unroll
  for (int m = 0; m < NMAT; m++)
#pragma unroll
    for (int nn = 0; nn < 2; nn++) acc[m][nn] = {0.f, 0.f, 0.f, 0.f};

  for (int k0 = 0; k0 < 512; k0 += 64) {
    // stage A (f32 weights -> bf16, swizzled): 32 rows x 64 cols per matrix
#pragma unroll
    for (int m = 0; m < NMAT; m++) {
      const float* wr = Ws[m] + (size_t)(o0 + ar) * 512 + k0 + ac8;
      const float4 a0 = *(const float4*)(wr);
      const float4 a1 = *(const float4*)(wr + 4);
      uint4 ua = {pack2(a0.x, a0.y), pack2(a0.z, a0.w),
                  pack2(a1.x, a1.y), pack2(a1.z, a1.w)};
      *(uint4*)(smem + m * 4096 + ar * 128 + ((2 * ac8) ^ swa)) = ua;
    }
    // stage B (transpose-pack [c][n] -> [n][c], swizzled)
    if constexpr (IN_F32) {
      const float* inb = (const float*)in + (size_t)b * 524288;
      const float* p0 = inb + (size_t)(k0 + kc2) * 1024 + n0 + kn8;
      union { float4 v[2]; float f[8]; } r0, r1;
      r0.v[0] = *(const float4*)p0;
      r0.v[1] = *(const float4*)(p0 + 4);
      r1.v[0] = *(const float4*)(p0 + 1024);
      r1.v[1] = *(const float4*)(p0 + 1028);
#pragma unroll
      for (int i = 0; i < 8; i++) {
        const int n = kn8 + i;
        *(unsigned*)(b_lds + n * 128 + ((2 * kc2) ^ ((n & 7) << 4))) =
            pack2(r0.f[i], r1.f[i]);
      }
    } else {
      const unsigned short* inb = (const unsigned short*)in + (size_t)b * 524288;
      union { uint4 v; unsigned short hw[8]; } r0, r1;
      r0.v = *(const uint4*)(inb + (size_t)(k0 + kc2) * 1024 + n0 + kn8);
      r1.v = *(const uint4*)(inb + (size_t)(k0 + kc2 + 1) * 1024 + n0 + kn8);
#pragma unroll
      for (int i = 0; i < 8; i++) {
        const int n = kn8 + i;
        const unsigned v32 = (unsigned)r0.hw[i] | ((unsigned)r1.hw[i] << 16);
        *(unsigned*)(b_lds + n * 128 + ((2 * kc2) ^ ((n & 7) << 4))) = v32;
      }
    }
    __syncthreads();
#pragma unroll
    for (int kk = 0; kk < 2; kk++) {
      bf16x8 bfr[2];
#pragma unroll
      for (int nn = 0; nn < 2; nn++) {
        const int n_loc = n_base + 16 * nn + cl;
        bfr[nn] = *(const bf16x8*)(b_lds + n_loc * 128 +
                                   ((64 * kk + 16 * rg) ^ ((n_loc & 7) << 4)));
      }
#pragma unroll
      for (int m = 0; m < NMAT; m++) {
        const int o_loc = o_base + cl;
        const bf16x8 af = *(const bf16x8*)(smem + m * 4096 + o_loc * 128 +
                                           ((64 * kk + 16 * rg) ^ ((o_loc & 7) << 4)));
#pragma unroll
        for (int nn = 0; nn < 2; nn++)
          acc[m][nn] = __builtin_amdgcn_mfma_f32_16x16x32_bf16(
              af, bfr[nn], acc[m][nn], 0, 0, 0);
      }
    }
    __syncthreads();
  }

  // epilogue per matrix: stage f32 [32][64] tile, coalesced store + bias
  float* o_st = (float*)smem;  // 8 KB
#pragma unroll
  for (int m = 0; m < NMAT; m++) {
    __syncthreads();
#pragma unroll
    for (int nn = 0; nn < 2; nn++)
#pragma unroll
      for (int r = 0; r < 4; r++)
        o_st[(o_base + 4 * rg + r) * 64 + n_base + 16 * nn + cl] = acc[m][nn][r];
    __syncthreads();
    {
      const int o_loc = t >> 3;
      const int en = (t & 7) * 8;
      const f32x4 v0 = *(const f32x4*)(o_st + o_loc * 64 + en);
      const f32x4 v1 = *(const f32x4*)(o_st + o_loc * 64 + en + 4);
      const float bv = Bs[m][o0 + o_loc];
      if constexpr (sizeof(OutT) == 2) {
        uint4 u = {pack2(v0[0] + bv, v0[1] + bv), pack2(v0[2] + bv, v0[3] + bv),
                   pack2(v1[0] + bv, v1[1] + bv), pack2(v1[2] + bv, v1[3] + bv)};
        *(uint4*)((bf16*)Os[m] + ((size_t)b * 512 + o0 + o_loc) * 1024 + n0 + en) = u;
      } else {
        float4 r0 = {v0[0] + bv, v0[1] + bv, v0[2] + bv, v0[3] + bv};
        float4 r1 = {v1[0] + bv, v1[1] + bv, v1[2] + bv, v1[3] + bv};
        float* dst = (float*)Os[m] + ((size_t)b * 512 + o0 + o_loc) * 1024 + n0 + en;
        *(float4*)dst = r0;
        *(float4*)(dst + 4) = r1;
      }
    }
  }
}

// depthwise 5x5 conv + LayerNorm(128) + GELU + 1x1(128->2) + tanh -> pos.
// (round-15 verbatim; verified)
__global__ __launch_bounds__(1024) void offset_kernel(
    const bf16* __restrict__ q, const float* __restrict__ dw_w,
    const float* __restrict__ dw_b, const float* __restrict__ ln_g,
    const float* __restrict__ ln_b, const float* __restrict__ off_w,
    float* __restrict__ pos, float* __restrict__ out_pos, float* __restrict__ out_ref) {
  __shared__ unsigned short q_s[5][36][128];  // 46080 B
  __shared__ float red_a[8][2][2];
  __shared__ float red_p[8][2][2];
  const int bg = blockIdx.x;
  const int h = blockIdx.y;
  const int b = bg >> 2, g = bg & 3;
  const int t = threadIdx.x;

  for (int task = t; task < 640; task += 1024) {
    const int ky = task >> 7, c = task & 127;
    const int y = h + ky - 2;
    if (y >= 0 && y < 32) {
      const unsigned short* qrow =
          (const unsigned short*)q + ((size_t)b * CDIM + g * GCH + c) * 1024 + y * 32;
      q_s[ky][0][c] = 0;
      q_s[ky][1][c] = 0;
#pragma unroll
      for (int x8 = 0; x8 < 4; x8++) {
        union { uint4 u; unsigned short s[8]; } vv;
        vv.u = *(const uint4*)(qrow + x8 * 8);
#pragma unroll
        for (int i = 0; i < 8; i++) q_s[ky][2 + x8 * 8 + i][c] = vv.s[i];
      }
      q_s[ky][34][c] = 0;
      q_s[ky][35][c] = 0;
    } else {
#pragma unroll
      for (int xi = 0; xi < 36; xi++) q_s[ky][xi][c] = 0;
    }
  }

  const int wslot = t >> 7;      // 0..7
  const int c = t & 127;
  const int half = c >> 6;
  const int lane = t & 63;
  float wgt[25];
#pragma unroll
  for (int i = 0; i < 25; i++) wgt[i] = dw_w[c * 25 + i];
  const float cbias = dw_b[c];
  const float gam = ln_g[c], bet = ln_b[c];
  const float ow0 = off_w[c], ow1 = off_w[GCH + c];
  __syncthreads();

  for (int j = 0; j < 4; j++) {
    const int w = wslot * 4 + j;
    float s = cbias;
#pragma unroll
    for (int ky = 0; ky < 5; ky++)
#pragma unroll
      for (int kx = 0; kx < 5; kx++)
        s += wgt[ky * 5 + kx] * bfu2f(q_s[ky][w + kx][c]);
    float ssum = s, ssq = s * s;
#pragma unroll
    for (int o = 1; o < 64; o <<= 1) {
      ssum += __shfl_xor(ssum, o);
      ssq += __shfl_xor(ssq, o);
    }
    if (lane == 0) { red_a[wslot][half][0] = ssum; red_a[wslot][half][1] = ssq; }
    __syncthreads();
    const float mu = (red_a[wslot][0][0] + red_a[wslot][1][0]) * (1.0f / 128.0f);
    const float var = (red_a[wslot][0][1] + red_a[wslot][1][1]) * (1.0f / 128.0f) - mu * mu;
    const float xn = (s - mu) * rsqrtf(var + 1e-5f) * gam + bet;
    const float ge = 0.5f * xn * (1.0f + erff(xn * 0.70710678118654752f));
    float p0 = ow0 * ge, p1 = ow1 * ge;
#pragma unroll
    for (int o = 1; o < 64; o <<= 1) {
      p0 += __shfl_xor(p0, o);
      p1 += __shfl_xor(p1, o);
    }
    if (lane == 0) { red_p[wslot][half][0] = p0; red_p[wslot][half][1] = p1; }
    __syncthreads();
    if (c == 0) {
      const float oy = tanhf(red_p[wslot][0][0] + red_p[wslot][1][0]) * 0.0625f;
      const float ox = tanhf(red_p[wslot][0][1] + red_p[wslot][1][1]) * 0.0625f;
      const float ry = ((float)h + 0.5f) * (2.0f / 32.0f) - 1.0f;
      const float rx = ((float)w + 0.5f) * (2.0f / 32.0f) - 1.0f;
      const float py = oy + ry, px = ox + rx;
      const size_t idx = (size_t)bg * 1024 + h * 32 + w;
      pos[idx * 2] = py;
      pos[idx * 2 + 1] = px;
      out_pos[idx * 2] = py;
      out_pos[idx * 2 + 1] = px;
      out_ref[idx * 2] = ry;
      out_ref[idx * 2 + 1] = rx;
    }
  }
}

// bilinear grid-sample of x at pos -> xs [16][128][1024]  (verbatim)
__global__ __launch_bounds__(256) void sample_kernel(
    const float* __restrict__ x, const float* __restrict__ pos, bf16* __restrict__ xs) {
  const int bg = blockIdx.x, c = blockIdx.y;
  const int b = bg >> 2, g = bg & 3;
  __shared__ float plane[1024];
  const float* xp = x + ((size_t)b * CDIM + g * GCH + c) * 1024;
  for (int i = threadIdx.x; i < 1024; i += 256) plane[i] = xp[i];
  __syncthreads();
  for (int s = threadIdx.x; s < 1024; s += 256) {
    const float py = pos[((size_t)bg * 1024 + s) * 2];
    const float px = pos[((size_t)bg * 1024 + s) * 2 + 1];
    const float gx = (px + 1.0f) * 15.5f;
    const float gy = (py + 1.0f) * 15.5f;
    const float x0f = floorf(gx), y0f = floorf(gy);
    const float wx = gx - x0f, wy = gy - y0f;
    const int ix = (int)x0f, iy = (int)y0f;
    float r = 0.0f;
    const bool vx0 = (ix >= 0) & (ix <= 31), vx1 = (ix + 1 >= 0) & (ix + 1 <= 31);
    const bool vy0 = (iy >= 0) & (iy <= 31), vy1 = (iy + 1 >= 0) & (iy + 1 <= 31);
    if (vy0 && vx0) r += plane[iy * 32 + ix] * (1.0f - wx) * (1.0f - wy);
    if (vy0 && vx1) r += plane[iy * 32 + ix + 1] * wx * (1.0f - wy);
    if (vy1 && vx0) r += plane[(iy + 1) * 32 + ix] * (1.0f - wx) * wy;
    if (vy1 && vx1) r += plane[(iy + 1) * 32 + ix + 1] * wx * wy;
    xs[((size_t)bg * GCH + c) * 1024 + s] = __float2bfloat16(r);
  }
}

// Swapped-operand MFMA attention, split-KV x2, P-overlays-K.
// (round-11/15 verbatim; verified 52 us)
__global__ __launch_bounds__(512) void attn_kernel(
    const bf16* __restrict__ q, const bf16* __restrict__ kk,
    const bf16* __restrict__ vv, const float* __restrict__ pos,
    const float* __restrict__ rpe, bf16* __restrict__ ao) {
  __shared__ __align__(16) unsigned char smem[51976];
  float* rpe_f = (float*)(smem + 32768);
  float* m_x = (float*)(smem + 50952);
  float* s_x = (float*)(smem + 51464);

  const int bh = blockIdx.y;
  const int m0 = blockIdx.x * 64;
  const int b = bh >> 3, h = bh & 7;
  const int g = h >> 1;
  const int bg = b * 4 + g;
  const int t = threadIdx.x, l = t & 63, w = t >> 6;
  const int wq = w & 3, half = w >> 2;
  const int rg = l >> 4, cl = l & 15;
  const int t2 = t & 255;
  const size_t hbase = ((size_t)b * CDIM + h * 64) * 1024;
  const unsigned short* qu = (const unsigned short*)q;

  unsigned char* k_base = smem + half * 8192;           // K, then P
  unsigned char* v_base = smem + 16384 + half * 8192;
  float* pos_a = (float*)(smem + 49928) + half * 128;

  for (int i = t; i < 65 * 66; i += 512) {
    const int y = i / 66, x = i - y * 66;
    float v = 0.0f;
    if (y >= 1 && y <= 63 && x >= 1 && x <= 63)
      v = rpe[h * 3969 + (y - 1) * 63 + (x - 1)];
    rpe_f[i] = v;
  }

  const int qloc = 16 * wq + cl;
  const int qm = m0 + qloc;
  const float qy15 = 15.5f * (((float)(qm >> 5) + 0.5f) * (2.0f / 32.0f) - 1.0f);
  const float qx15 = 15.5f * (((float)(qm & 31) + 0.5f) * (2.0f / 32.0f) - 1.0f);

  bf16x8 bq[2];
#pragma unroll
  for (int kc = 0; kc < 2; kc++) {
    bf16x8 a;
#pragma unroll
    for (int j = 0; j < 8; j++)
      a[j] = (short)qu[hbase + (size_t)(32 * kc + 8 * rg + j) * 1024 + qm];
    bq[kc] = a;
  }

  float rmax = -1e30f, rsum = 0.0f;
  f32x4 oacc[4] = {{0.f,0.f,0.f,0.f},{0.f,0.f,0.f,0.f},
                   {0.f,0.f,0.f,0.f},{0.f,0.f,0.f,0.f}};

  const float* posb = pos + (size_t)bg * 2048;
  const unsigned swl = (unsigned)((cl & 7) << 4);
  const int kc2 = (t2 & 31) * 2;
  const int kn8 = (t2 >> 5) * 8;
  const int vc = t2 >> 2;
  const int vh = (t2 & 3) * 32;

  for (int tile = 0; tile < 8; tile++) {
    const int n0 = half * 512 + tile * 64;
    {
      union { uint4 v; unsigned short hw[8]; } r0, r1;
      r0.v = *(const uint4*)(kk + hbase + (size_t)kc2 * 1024 + n0 + kn8);
      r1.v = *(const uint4*)(kk + hbase + (size_t)(kc2 + 1) * 1024 + n0 + kn8);
#pragma unroll
      for (int i = 0; i < 8; i++) {
        const int n = kn8 + i;
        const unsigned v32 = (unsigned)r0.hw[i] | ((unsigned)r1.hw[i] << 16);
        *(unsigned*)(k_base + n * 128 + ((kc2 * 2) ^ ((n & 7) << 4))) = v32;
      }
      const uint4 s0 = *(const uint4*)(vv + hbase + (size_t)vc * 1024 + n0 + vh / 2);
      const uint4 s1 = *(const uint4*)(vv + hbase + (size_t)vc * 1024 + n0 + vh / 2 + 8);
      *(uint4*)(v_base + vc * 128 + (vh ^ ((vc & 7) << 4))) = s0;
      *(uint4*)(v_base + vc * 128 + ((vh + 16) ^ ((vc & 7) << 4))) = s1;
      if (t2 < 128) pos_a[t2] = 31.0f - 15.5f * posb[2 * n0 + t2];
    }
    __syncthreads();  // staged K/V/pos visible

    f32x4 sf[4];
#pragma unroll
    for (int tn = 0; tn < 4; tn++) {
      const int nrow = 16 * tn + cl;
      const bf16x8 a0 = *(const bf16x8*)(k_base + nrow * 128 + ((16 * rg) ^ swl));
      const bf16x8 a1 = *(const bf16x8*)(k_base + nrow * 128 + ((64 + 16 * rg) ^ swl));
      f32x4 z = {0.f, 0.f, 0.f, 0.f};
      z = __builtin_amdgcn_mfma_f32_16x16x32_bf16(a0, bq[0], z, 0, 0, 0);
      z = __builtin_amdgcn_mfma_f32_16x16x32_bf16(a1, bq[1], z, 0, 0, 0);
      sf[tn] = z;
    }

#pragma unroll
    for (int tn = 0; tn < 4; tn++)
#pragma unroll
      for (int r = 0; r < 4; r++) {
        const int key = 16 * tn + 4 * rg + r;
        const float gyc = qy15 + pos_a[2 * key];
        const float gxc = qx15 + pos_a[2 * key + 1];
        const float y0f = floorf(gyc), x0f = floorf(gxc);
        const float wy = gyc - y0f, wx = gxc - x0f;
        const int iy1 = (int)y0f + 1, ix1 = (int)x0f + 1;
        const float* tp = rpe_f + iy1 * 66 + ix1;
        const float t00 = tp[0], t01 = tp[1];
        const float t10 = tp[66], t11 = tp[67];
        const float r0v = t00 + (t01 - t00) * wx;
        const float r1v = t10 + (t11 - t10) * wx;
        const float bias = r0v + (r1v - r0v) * wy;
        sf[tn][r] = sf[tn][r] * 0.125f + bias;
      }

    float tmax = sf[0][0];
#pragma unroll
    for (int tn = 0; tn < 4; tn++)
#pragma unroll
      for (int r = 0; r < 4; r++) tmax = fmaxf(tmax, sf[tn][r]);
    tmax = fmaxf(tmax, __shfl_xor(tmax, 16));
    tmax = fmaxf(tmax, __shfl_xor(tmax, 32));
    const float nmax = fmaxf(rmax, tmax);
    const float corr = __expf(rmax - nmax);
    rmax = nmax;
    float lsum = 0.0f;
    unsigned pw[8];
#pragma unroll
    for (int tn = 0; tn < 4; tn++) {
      const float p0 = __expf(sf[tn][0] - nmax);
      const float p1 = __expf(sf[tn][1] - nmax);
      const float p2 = __expf(sf[tn][2] - nmax);
      const float p3 = __expf(sf[tn][3] - nmax);
      lsum += (p0 + p1) + (p2 + p3);
      pw[2 * tn] = pack2(p0, p1);
      pw[2 * tn + 1] = pack2(p2, p3);
    }
    lsum += __shfl_xor(lsum, 16);
    lsum += __shfl_xor(lsum, 32);
    rsum = rsum * corr + lsum;
#pragma unroll
    for (int tc = 0; tc < 4; tc++) {
      oacc[tc][0] *= corr; oacc[tc][1] *= corr;
      oacc[tc][2] *= corr; oacc[tc][3] *= corr;
    }

    __syncthreads();  // all waves' QK reads of k_base complete before P overlay

#pragma unroll
    for (int tn = 0; tn < 4; tn++) {
      *(unsigned*)(k_base + qloc * 128 + ((2 * (16 * tn + 4 * rg)) ^ swl)) = pw[2 * tn];
      *(unsigned*)(k_base + qloc * 128 + ((2 * (16 * tn + 4 * rg) + 4) ^ swl)) = pw[2 * tn + 1];
    }

#pragma unroll
    for (int kc = 0; kc < 2; kc++) {
      const bf16x8 pb = *(const bf16x8*)(k_base + qloc * 128 + ((2 * (32 * kc + 8 * rg)) ^ swl));
#pragma unroll
      for (int tc = 0; tc < 4; tc++) {
        const int crow = 16 * tc + cl;
        const bf16x8 av = *(const bf16x8*)(v_base + crow * 128 + ((2 * (32 * kc + 8 * rg)) ^ swl));
        oacc[tc] = __builtin_amdgcn_mfma_f32_16x16x32_bf16(av, pb, oacc[tc], 0, 0, 0);
      }
    }
    __syncthreads();  // P/V reads done before next stage overwrites
  }

  if (l < 16) {
    m_x[half * 64 + wq * 16 + cl] = rmax;
    s_x[half * 64 + wq * 16 + cl] = rsum;
  }
  __syncthreads();
  const float m0v = m_x[wq * 16 + cl], m1v = m_x[64 + wq * 16 + cl];
  const float s0v = s_x[wq * 16 + cl], s1v = s_x[64 + wq * 16 + cl];
  const float M = fmaxf(m0v, m1v);
  const float f0 = __expf(m0v - M), f1 = __expf(m1v - M);
  const float inv = 1.0f / (f0 * s0v + f1 * s1v);
  const float scale = (half == 0 ? f0 : f1) * inv;
  float* o_st = (float*)smem;  // [64 c][66] f32
  if (half == 0) {
#pragma unroll
    for (int tc = 0; tc < 4; tc++)
#pragma unroll
      for (int r = 0; r < 4; r++)
        o_st[(16 * tc + 4 * rg + r) * 66 + qloc] = oacc[tc][r] * scale;
  }
  __syncthreads();
  if (half == 1) {
#pragma unroll
    for (int tc = 0; tc < 4; tc++)
#pragma unroll
      for (int r = 0; r < 4; r++)
        o_st[(16 * tc + 4 * rg + r) * 66 + qloc] += oacc[tc][r] * scale;
  }
  __syncthreads();
  {
    const int c = t >> 3, mq = (t & 7) * 8;
    unsigned u[4];
#pragma unroll
    for (int i = 0; i < 4; i++)
      u[i] = pack2(o_st[c * 66 + mq + 2 * i], o_st[c * 66 + mq + 2 * i + 1]);
    uint4 outv = {u[0], u[1], u[2], u[3]};
    *(uint4*)(ao + hbase + (size_t)c * 1024 + m0 + mq) = outv;
  }
}

extern "C" void kernel_launch(void* const* d_in, const int* in_sizes, int n_in,
                              void* d_out, int out_size, void* d_ws, size_t ws_size,
                              hipStream_t stream) {
  const float* x    = (const float*)d_in[0];
  const float* w_q  = (const float*)d_in[1];
  const float* b_q  = (const float*)d_in[2];
  const float* w_k  = (const float*)d_in[3];
  const float* b_k  = (const float*)d_in[4];
  const float* w_v  = (const float*)d_in[5];
  const float* b_v  = (const float*)d_in[6];
  const float* w_o  = (const float*)d_in[7];
  const float* b_o  = (const float*)d_in[8];
  const float* dw_w = (const float*)d_in[9];
  const float* dw_b = (const float*)d_in[10];
  const float* ln_g = (const float*)d_in[11];
  const float* ln_b = (const float*)d_in[12];
  const float* off_w= (const float*)d_in[13];
  const float* rpe  = (const float*)d_in[14];

  // Outputs are FLOAT32 (reference returns f32 arrays).
  float* out_y   = (float*)d_out;            // [4,512,32,32]   (2097152 f32)
  float* out_pos = out_y + 2097152;          // [4,4,32,32,2]   (32768 f32)
  float* out_ref = out_pos + 32768;          // [4,4,32,32,2]   (32768 f32)

  // workspace (~16.1 MB): pos f32, then bf16 buffers.
  float* pos_ws = (float*)d_ws;              // 32768 f32
  bf16*  q_ws   = (bf16*)(pos_ws + 32768);   // 2097152 bf16
  bf16*  xs_ws  = q_ws + 2097152;            // 2097152 (reused as ao)
  bf16*  k_ws   = xs_ws + 2097152;           // 2097152
  bf16*  v_ws   = k_ws + 2097152;            // 2097152
  bf16*  ao_ws  = xs_ws;                     // xs dead after k/v gemm

  gemm_kernel<true, bf16, 1><<<dim3(16, 16, 4), 256, 0, stream>>>(
      w_q, b_q, nullptr, nullptr, x, q_ws, (bf16*)nullptr);
  offset_kernel<<<dim3(16, 32), 1024, 0, stream>>>(q_ws, dw_w, dw_b, ln_g, ln_b, off_w,
                                                   pos_ws, out_pos, out_ref);
  sample_kernel<<<dim3(16, 128), 256, 0, stream>>>(x, pos_ws, xs_ws);
  gemm_kernel<false, bf16, 2><<<dim3(16, 16, 4), 256, 0, stream>>>(
      w_k, b_k, w_v, b_v, xs_ws, k_ws, v_ws);
  attn_kernel<<<dim3(16, 32), 512, 0, stream>>>(q_ws, k_ws, v_ws, pos_ws, rpe, ao_ws);
  gemm_kernel<false, float, 1><<<dim3(16, 16, 4), 256, 0, stream>>>(
      w_o, b_o, nullptr, nullptr, ao_ws, out_y, (float*)nullptr);
}

// Round 19
// 111.257 us; speedup vs baseline: 1.1608x; 1.1608x over previous
//
#include <hip/hip_runtime.h>
#include <hip/hip_bf16.h>

typedef __hip_bfloat16 bf16;
typedef __attribute__((ext_vector_type(8))) short bf16x8;
typedef __attribute__((ext_vector_type(4))) float f32x4;

#define BDIM 4
#define CDIM 512
#define NHEADS 8
#define NGROUPS 4
#define GCH 128

__device__ __forceinline__ float bf2f(bf16 v) { return __bfloat162float(v); }
__device__ __forceinline__ float bfu2f(unsigned short u) {
  return __uint_as_float(((unsigned)u) << 16);
}
__device__ __forceinline__ unsigned short f2bu(float v) {
  return __hip_bfloat16_raw(__float2bfloat16(v)).x;
}
__device__ __forceinline__ unsigned pack2(float lo, float hi) {
  return (unsigned)f2bu(lo) | ((unsigned)f2bu(hi) << 16);
}

// ---- MFMA GEMM: out_m[b][o][n] = sum_c Wm[o][c]*in[b][c][n] + bias_m[o] ----
// (round-11/15 verbatim; verified — the 64x64-tile form is the local optimum:
// r17 in-block split-K and r18 32x64-tile both regressed)
template <bool IN_F32, typename OutT, int NMAT>
__global__ __launch_bounds__(256) void gemm_kernel(
    const float* __restrict__ W0, const float* __restrict__ bias0,
    const float* __restrict__ W1, const float* __restrict__ bias1,
    const void* __restrict__ in,
    OutT* __restrict__ out0, OutT* __restrict__ out1) {
  __shared__ __align__(16) unsigned char smem[8192 * (NMAT + 1)];
  unsigned char* b_lds = smem + 8192 * NMAT;  // [64 n][64 c] bf16 swz
  const int b = blockIdx.z;
  const int o0 = blockIdx.y * 64;
  const int n0 = blockIdx.x * 64;
  const int t = threadIdx.x, l = t & 63, w = t >> 6;
  const int rg = l >> 4, cl = l & 15;
  const int o_base = (w >> 1) * 32, n_base = (w & 1) * 32;
  const int ao = t >> 2;
  const int ac8 = (t & 3) * 8;
  const int kc2 = (t & 31) * 2;
  const int kn8 = (t >> 5) * 8;
  const unsigned swo = (unsigned)((ao & 7) << 4);
  const float* Ws[2] = {W0, W1};
  const float* Bs[2] = {bias0, bias1};
  OutT* Os[2] = {out0, out1};

  f32x4 acc[NMAT][2][2];
#pragma unroll
  for (int m = 0; m < NMAT; m++)
#pragma unroll
    for (int i = 0; i < 2; i++)
#pragma unroll
      for (int j = 0; j < 2; j++) acc[m][i][j] = {0.f, 0.f, 0.f, 0.f};

  for (int k0 = 0; k0 < 512; k0 += 64) {
#pragma unroll
    for (int m = 0; m < NMAT; m++) {
      const float* wr = Ws[m] + (size_t)(o0 + ao) * 512 + k0;
      const float4 a0 = *(const float4*)(wr + ac8);
      const float4 a1 = *(const float4*)(wr + ac8 + 4);
      const float4 c0 = *(const float4*)(wr + ac8 + 32);
      const float4 c1 = *(const float4*)(wr + ac8 + 36);
      uint4 ua = {pack2(a0.x, a0.y), pack2(a0.z, a0.w),
                  pack2(a1.x, a1.y), pack2(a1.z, a1.w)};
      uint4 ub = {pack2(c0.x, c0.y), pack2(c0.z, c0.w),
                  pack2(c1.x, c1.y), pack2(c1.z, c1.w)};
      unsigned char* am = smem + 8192 * m;
      *(uint4*)(am + ao * 128 + ((2 * ac8) ^ swo)) = ua;
      *(uint4*)(am + ao * 128 + ((2 * ac8 + 64) ^ swo)) = ub;
    }
    if constexpr (IN_F32) {
      const float* inb = (const float*)in + (size_t)b * 524288;
      const float* p0 = inb + (size_t)(k0 + kc2) * 1024 + n0 + kn8;
      union { float4 v[2]; float f[8]; } r0, r1;
      r0.v[0] = *(const float4*)p0;
      r0.v[1] = *(const float4*)(p0 + 4);
      r1.v[0] = *(const float4*)(p0 + 1024);
      r1.v[1] = *(const float4*)(p0 + 1028);
#pragma unroll
      for (int i = 0; i < 8; i++) {
        const int n = kn8 + i;
        *(unsigned*)(b_lds + n * 128 + ((2 * kc2) ^ ((n & 7) << 4))) =
            pack2(r0.f[i], r1.f[i]);
      }
    } else {
      const unsigned short* inb = (const unsigned short*)in + (size_t)b * 524288;
      union { uint4 v; unsigned short hw[8]; } r0, r1;
      r0.v = *(const uint4*)(inb + (size_t)(k0 + kc2) * 1024 + n0 + kn8);
      r1.v = *(const uint4*)(inb + (size_t)(k0 + kc2 + 1) * 1024 + n0 + kn8);
#pragma unroll
      for (int i = 0; i < 8; i++) {
        const int n = kn8 + i;
        const unsigned v32 = (unsigned)r0.hw[i] | ((unsigned)r1.hw[i] << 16);
        *(unsigned*)(b_lds + n * 128 + ((2 * kc2) ^ ((n & 7) << 4))) = v32;
      }
    }
    __syncthreads();
#pragma unroll
    for (int kk = 0; kk < 2; kk++) {
      bf16x8 bfr[2];
#pragma unroll
      for (int nn = 0; nn < 2; nn++) {
        const int n_loc = n_base + 16 * nn + cl;
        bfr[nn] = *(const bf16x8*)(b_lds + n_loc * 128 +
                                   ((64 * kk + 16 * rg) ^ ((n_loc & 7) << 4)));
      }
#pragma unroll
      for (int m = 0; m < NMAT; m++) {
        bf16x8 af[2];
#pragma unroll
        for (int mi = 0; mi < 2; mi++) {
          const int o_loc = o_base + 16 * mi + cl;
          af[mi] = *(const bf16x8*)(smem + 8192 * m + o_loc * 128 +
                                    ((64 * kk + 16 * rg) ^ ((o_loc & 7) << 4)));
        }
#pragma unroll
        for (int mi = 0; mi < 2; mi++)
#pragma unroll
          for (int nn = 0; nn < 2; nn++)
            acc[m][mi][nn] = __builtin_amdgcn_mfma_f32_16x16x32_bf16(
                af[mi], bfr[nn], acc[m][mi][nn], 0, 0, 0);
      }
    }
    __syncthreads();
  }

  float* o_st = (float*)smem;  // [64][64]
#pragma unroll
  for (int m = 0; m < NMAT; m++) {
    __syncthreads();
#pragma unroll
    for (int mi = 0; mi < 2; mi++)
#pragma unroll
      for (int nn = 0; nn < 2; nn++)
#pragma unroll
        for (int r = 0; r < 4; r++)
          o_st[(o_base + 16 * mi + 4 * rg + r) * 64 + n_base + 16 * nn + cl] =
              acc[m][mi][nn][r];
    __syncthreads();
    const int eo = t >> 4;
    const int en = (t & 15) * 4;
#pragma unroll
    for (int pass = 0; pass < 4; pass++) {
      const int o_loc = eo + pass * 16;
      const f32x4 v = *(const f32x4*)(o_st + o_loc * 64 + en);
      const float bv = Bs[m][o0 + o_loc];
      if constexpr (sizeof(OutT) == 2) {
        ushort4 u;
        u.x = f2bu(v[0] + bv);
        u.y = f2bu(v[1] + bv);
        u.z = f2bu(v[2] + bv);
        u.w = f2bu(v[3] + bv);
        *(ushort4*)((bf16*)Os[m] + ((size_t)b * 512 + o0 + o_loc) * 1024 + n0 + en) = u;
      } else {
        float4 r = {v[0] + bv, v[1] + bv, v[2] + bv, v[3] + bv};
        *(float4*)((float*)Os[m] + ((size_t)b * 512 + o0 + o_loc) * 1024 + n0 + en) = r;
      }
    }
  }
}

// depthwise 5x5 conv + LayerNorm(128) + GELU + 1x1(128->2) + tanh -> pos.
// (round-15 verbatim; verified)
__global__ __launch_bounds__(1024) void offset_kernel(
    const bf16* __restrict__ q, const float* __restrict__ dw_w,
    const float* __restrict__ dw_b, const float* __restrict__ ln_g,
    const float* __restrict__ ln_b, const float* __restrict__ off_w,
    float* __restrict__ pos, float* __restrict__ out_pos, float* __restrict__ out_ref) {
  __shared__ unsigned short q_s[5][36][128];  // 46080 B
  __shared__ float red_a[8][2][2];
  __shared__ float red_p[8][2][2];
  const int bg = blockIdx.x;
  const int h = blockIdx.y;
  const int b = bg >> 2, g = bg & 3;
  const int t = threadIdx.x;

  for (int task = t; task < 640; task += 1024) {
    const int ky = task >> 7, c = task & 127;
    const int y = h + ky - 2;
    if (y >= 0 && y < 32) {
      const unsigned short* qrow =
          (const unsigned short*)q + ((size_t)b * CDIM + g * GCH + c) * 1024 + y * 32;
      q_s[ky][0][c] = 0;
      q_s[ky][1][c] = 0;
#pragma unroll
      for (int x8 = 0; x8 < 4; x8++) {
        union { uint4 u; unsigned short s[8]; } vv;
        vv.u = *(const uint4*)(qrow + x8 * 8);
#pragma unroll
        for (int i = 0; i < 8; i++) q_s[ky][2 + x8 * 8 + i][c] = vv.s[i];
      }
      q_s[ky][34][c] = 0;
      q_s[ky][35][c] = 0;
    } else {
#pragma unroll
      for (int xi = 0; xi < 36; xi++) q_s[ky][xi][c] = 0;
    }
  }

  const int wslot = t >> 7;      // 0..7
  const int c = t & 127;
  const int half = c >> 6;
  const int lane = t & 63;
  float wgt[25];
#pragma unroll
  for (int i = 0; i < 25; i++) wgt[i] = dw_w[c * 25 + i];
  const float cbias = dw_b[c];
  const float gam = ln_g[c], bet = ln_b[c];
  const float ow0 = off_w[c], ow1 = off_w[GCH + c];
  __syncthreads();

  for (int j = 0; j < 4; j++) {
    const int w = wslot * 4 + j;
    float s = cbias;
#pragma unroll
    for (int ky = 0; ky < 5; ky++)
#pragma unroll
      for (int kx = 0; kx < 5; kx++)
        s += wgt[ky * 5 + kx] * bfu2f(q_s[ky][w + kx][c]);
    float ssum = s, ssq = s * s;
#pragma unroll
    for (int o = 1; o < 64; o <<= 1) {
      ssum += __shfl_xor(ssum, o);
      ssq += __shfl_xor(ssq, o);
    }
    if (lane == 0) { red_a[wslot][half][0] = ssum; red_a[wslot][half][1] = ssq; }
    __syncthreads();
    const float mu = (red_a[wslot][0][0] + red_a[wslot][1][0]) * (1.0f / 128.0f);
    const float var = (red_a[wslot][0][1] + red_a[wslot][1][1]) * (1.0f / 128.0f) - mu * mu;
    const float xn = (s - mu) * rsqrtf(var + 1e-5f) * gam + bet;
    const float ge = 0.5f * xn * (1.0f + erff(xn * 0.70710678118654752f));
    float p0 = ow0 * ge, p1 = ow1 * ge;
#pragma unroll
    for (int o = 1; o < 64; o <<= 1) {
      p0 += __shfl_xor(p0, o);
      p1 += __shfl_xor(p1, o);
    }
    if (lane == 0) { red_p[wslot][half][0] = p0; red_p[wslot][half][1] = p1; }
    __syncthreads();
    if (c == 0) {
      const float oy = tanhf(red_p[wslot][0][0] + red_p[wslot][1][0]) * 0.0625f;
      const float ox = tanhf(red_p[wslot][0][1] + red_p[wslot][1][1]) * 0.0625f;
      const float ry = ((float)h + 0.5f) * (2.0f / 32.0f) - 1.0f;
      const float rx = ((float)w + 0.5f) * (2.0f / 32.0f) - 1.0f;
      const float py = oy + ry, px = ox + rx;
      const size_t idx = (size_t)bg * 1024 + h * 32 + w;
      pos[idx * 2] = py;
      pos[idx * 2 + 1] = px;
      out_pos[idx * 2] = py;
      out_pos[idx * 2 + 1] = px;
      out_ref[idx * 2] = ry;
      out_ref[idx * 2 + 1] = rx;
    }
  }
}

// bilinear grid-sample of x at pos -> xs [16][128][1024]  (verbatim)
__global__ __launch_bounds__(256) void sample_kernel(
    const float* __restrict__ x, const float* __restrict__ pos, bf16* __restrict__ xs) {
  const int bg = blockIdx.x, c = blockIdx.y;
  const int b = bg >> 2, g = bg & 3;
  __shared__ float plane[1024];
  const float* xp = x + ((size_t)b * CDIM + g * GCH + c) * 1024;
  for (int i = threadIdx.x; i < 1024; i += 256) plane[i] = xp[i];
  __syncthreads();
  for (int s = threadIdx.x; s < 1024; s += 256) {
    const float py = pos[((size_t)bg * 1024 + s) * 2];
    const float px = pos[((size_t)bg * 1024 + s) * 2 + 1];
    const float gx = (px + 1.0f) * 15.5f;
    const float gy = (py + 1.0f) * 15.5f;
    const float x0f = floorf(gx), y0f = floorf(gy);
    const float wx = gx - x0f, wy = gy - y0f;
    const int ix = (int)x0f, iy = (int)y0f;
    float r = 0.0f;
    const bool vx0 = (ix >= 0) & (ix <= 31), vx1 = (ix + 1 >= 0) & (ix + 1 <= 31);
    const bool vy0 = (iy >= 0) & (iy <= 31), vy1 = (iy + 1 >= 0) & (iy + 1 <= 31);
    if (vy0 && vx0) r += plane[iy * 32 + ix] * (1.0f - wx) * (1.0f - wy);
    if (vy0 && vx1) r += plane[iy * 32 + ix + 1] * wx * (1.0f - wy);
    if (vy1 && vx0) r += plane[(iy + 1) * 32 + ix] * (1.0f - wx) * wy;
    if (vy1 && vx1) r += plane[(iy + 1) * 32 + ix + 1] * wx * wy;
    xs[((size_t)bg * GCH + c) * 1024 + s] = __float2bfloat16(r);
  }
}

// Swapped-operand MFMA attention, split-KV x2, P-overlays-K.
// (round-11/15 verbatim; verified 52 us)
__global__ __launch_bounds__(512) void attn_kernel(
    const bf16* __restrict__ q, const bf16* __restrict__ kk,
    const bf16* __restrict__ vv, const float* __restrict__ pos,
    const float* __restrict__ rpe, bf16* __restrict__ ao) {
  __shared__ __align__(16) unsigned char smem[51976];
  float* rpe_f = (float*)(smem + 32768);
  float* m_x = (float*)(smem + 50952);
  float* s_x = (float*)(smem + 51464);

  const int bh = blockIdx.y;
  const int m0 = blockIdx.x * 64;
  const int b = bh >> 3, h = bh & 7;
  const int g = h >> 1;
  const int bg = b * 4 + g;
  const int t = threadIdx.x, l = t & 63, w = t >> 6;
  const int wq = w & 3, half = w >> 2;
  const int rg = l >> 4, cl = l & 15;
  const int t2 = t & 255;
  const size_t hbase = ((size_t)b * CDIM + h * 64) * 1024;
  const unsigned short* qu = (const unsigned short*)q;

  unsigned char* k_base = smem + half * 8192;           // K, then P
  unsigned char* v_base = smem + 16384 + half * 8192;
  float* pos_a = (float*)(smem + 49928) + half * 128;

  for (int i = t; i < 65 * 66; i += 512) {
    const int y = i / 66, x = i - y * 66;
    float v = 0.0f;
    if (y >= 1 && y <= 63 && x >= 1 && x <= 63)
      v = rpe[h * 3969 + (y - 1) * 63 + (x - 1)];
    rpe_f[i] = v;
  }

  const int qloc = 16 * wq + cl;
  const int qm = m0 + qloc;
  const float qy15 = 15.5f * (((float)(qm >> 5) + 0.5f) * (2.0f / 32.0f) - 1.0f);
  const float qx15 = 15.5f * (((float)(qm & 31) + 0.5f) * (2.0f / 32.0f) - 1.0f);

  bf16x8 bq[2];
#pragma unroll
  for (int kc = 0; kc < 2; kc++) {
    bf16x8 a;
#pragma unroll
    for (int j = 0; j < 8; j++)
      a[j] = (short)qu[hbase + (size_t)(32 * kc + 8 * rg + j) * 1024 + qm];
    bq[kc] = a;
  }

  float rmax = -1e30f, rsum = 0.0f;
  f32x4 oacc[4] = {{0.f,0.f,0.f,0.f},{0.f,0.f,0.f,0.f},
                   {0.f,0.f,0.f,0.f},{0.f,0.f,0.f,0.f}};

  const float* posb = pos + (size_t)bg * 2048;
  const unsigned swl = (unsigned)((cl & 7) << 4);
  const int kc2 = (t2 & 31) * 2;
  const int kn8 = (t2 >> 5) * 8;
  const int vc = t2 >> 2;
  const int vh = (t2 & 3) * 32;

  for (int tile = 0; tile < 8; tile++) {
    const int n0 = half * 512 + tile * 64;
    {
      union { uint4 v; unsigned short hw[8]; } r0, r1;
      r0.v = *(const uint4*)(kk + hbase + (size_t)kc2 * 1024 + n0 + kn8);
      r1.v = *(const uint4*)(kk + hbase + (size_t)(kc2 + 1) * 1024 + n0 + kn8);
#pragma unroll
      for (int i = 0; i < 8; i++) {
        const int n = kn8 + i;
        const unsigned v32 = (unsigned)r0.hw[i] | ((unsigned)r1.hw[i] << 16);
        *(unsigned*)(k_base + n * 128 + ((kc2 * 2) ^ ((n & 7) << 4))) = v32;
      }
      const uint4 s0 = *(const uint4*)(vv + hbase + (size_t)vc * 1024 + n0 + vh / 2);
      const uint4 s1 = *(const uint4*)(vv + hbase + (size_t)vc * 1024 + n0 + vh / 2 + 8);
      *(uint4*)(v_base + vc * 128 + (vh ^ ((vc & 7) << 4))) = s0;
      *(uint4*)(v_base + vc * 128 + ((vh + 16) ^ ((vc & 7) << 4))) = s1;
      if (t2 < 128) pos_a[t2] = 31.0f - 15.5f * posb[2 * n0 + t2];
    }
    __syncthreads();  // staged K/V/pos visible

    f32x4 sf[4];
#pragma unroll
    for (int tn = 0; tn < 4; tn++) {
      const int nrow = 16 * tn + cl;
      const bf16x8 a0 = *(const bf16x8*)(k_base + nrow * 128 + ((16 * rg) ^ swl));
      const bf16x8 a1 = *(const bf16x8*)(k_base + nrow * 128 + ((64 + 16 * rg) ^ swl));
      f32x4 z = {0.f, 0.f, 0.f, 0.f};
      z = __builtin_amdgcn_mfma_f32_16x16x32_bf16(a0, bq[0], z, 0, 0, 0);
      z = __builtin_amdgcn_mfma_f32_16x16x32_bf16(a1, bq[1], z, 0, 0, 0);
      sf[tn] = z;
    }

#pragma unroll
    for (int tn = 0; tn < 4; tn++)
#pragma unroll
      for (int r = 0; r < 4; r++) {
        const int key = 16 * tn + 4 * rg + r;
        const float gyc = qy15 + pos_a[2 * key];
        const float gxc = qx15 + pos_a[2 * key + 1];
        const float y0f = floorf(gyc), x0f = floorf(gxc);
        const float wy = gyc - y0f, wx = gxc - x0f;
        const int iy1 = (int)y0f + 1, ix1 = (int)x0f + 1;
        const float* tp = rpe_f + iy1 * 66 + ix1;
        const float t00 = tp[0], t01 = tp[1];
        const float t10 = tp[66], t11 = tp[67];
        const float r0v = t00 + (t01 - t00) * wx;
        const float r1v = t10 + (t11 - t10) * wx;
        const float bias = r0v + (r1v - r0v) * wy;
        sf[tn][r] = sf[tn][r] * 0.125f + bias;
      }

    float tmax = sf[0][0];
#pragma unroll
    for (int tn = 0; tn < 4; tn++)
#pragma unroll
      for (int r = 0; r < 4; r++) tmax = fmaxf(tmax, sf[tn][r]);
    tmax = fmaxf(tmax, __shfl_xor(tmax, 16));
    tmax = fmaxf(tmax, __shfl_xor(tmax, 32));
    const float nmax = fmaxf(rmax, tmax);
    const float corr = __expf(rmax - nmax);
    rmax = nmax;
    float lsum = 0.0f;
    unsigned pw[8];
#pragma unroll
    for (int tn = 0; tn < 4; tn++) {
      const float p0 = __expf(sf[tn][0] - nmax);
      const float p1 = __expf(sf[tn][1] - nmax);
      const float p2 = __expf(sf[tn][2] - nmax);
      const float p3 = __expf(sf[tn][3] - nmax);
      lsum += (p0 + p1) + (p2 + p3);
      pw[2 * tn] = pack2(p0, p1);
      pw[2 * tn + 1] = pack2(p2, p3);
    }
    lsum += __shfl_xor(lsum, 16);
    lsum += __shfl_xor(lsum, 32);
    rsum = rsum * corr + lsum;
#pragma unroll
    for (int tc = 0; tc < 4; tc++) {
      oacc[tc][0] *= corr; oacc[tc][1] *= corr;
      oacc[tc][2] *= corr; oacc[tc][3] *= corr;
    }

    __syncthreads();  // all waves' QK reads of k_base complete before P overlay

#pragma unroll
    for (int tn = 0; tn < 4; tn++) {
      *(unsigned*)(k_base + qloc * 128 + ((2 * (16 * tn + 4 * rg)) ^ swl)) = pw[2 * tn];
      *(unsigned*)(k_base + qloc * 128 + ((2 * (16 * tn + 4 * rg) + 4) ^ swl)) = pw[2 * tn + 1];
    }

#pragma unroll
    for (int kc = 0; kc < 2; kc++) {
      const bf16x8 pb = *(const bf16x8*)(k_base + qloc * 128 + ((2 * (32 * kc + 8 * rg)) ^ swl));
#pragma unroll
      for (int tc = 0; tc < 4; tc++) {
        const int crow = 16 * tc + cl;
        const bf16x8 av = *(const bf16x8*)(v_base + crow * 128 + ((2 * (32 * kc + 8 * rg)) ^ swl));
        oacc[tc] = __builtin_amdgcn_mfma_f32_16x16x32_bf16(av, pb, oacc[tc], 0, 0, 0);
      }
    }
    __syncthreads();  // P/V reads done before next stage overwrites
  }

  if (l < 16) {
    m_x[half * 64 + wq * 16 + cl] = rmax;
    s_x[half * 64 + wq * 16 + cl] = rsum;
  }
  __syncthreads();
  const float m0v = m_x[wq * 16 + cl], m1v = m_x[64 + wq * 16 + cl];
  const float s0v = s_x[wq * 16 + cl], s1v = s_x[64 + wq * 16 + cl];
  const float M = fmaxf(m0v, m1v);
  const float f0 = __expf(m0v - M), f1 = __expf(m1v - M);
  const float inv = 1.0f / (f0 * s0v + f1 * s1v);
  const float scale = (half == 0 ? f0 : f1) * inv;
  float* o_st = (float*)smem;  // [64 c][66] f32
  if (half == 0) {
#pragma unroll
    for (int tc = 0; tc < 4; tc++)
#pragma unroll
      for (int r = 0; r < 4; r++)
        o_st[(16 * tc + 4 * rg + r) * 66 + qloc] = oacc[tc][r] * scale;
  }
  __syncthreads();
  if (half == 1) {
#pragma unroll
    for (int tc = 0; tc < 4; tc++)
#pragma unroll
      for (int r = 0; r < 4; r++)
        o_st[(16 * tc + 4 * rg + r) * 66 + qloc] += oacc[tc][r] * scale;
  }
  __syncthreads();
  {
    const int c = t >> 3, mq = (t & 7) * 8;
    unsigned u[4];
#pragma unroll
    for (int i = 0; i < 4; i++)
      u[i] = pack2(o_st[c * 66 + mq + 2 * i], o_st[c * 66 + mq + 2 * i + 1]);
    uint4 outv = {u[0], u[1], u[2], u[3]};
    *(uint4*)(ao + hbase + (size_t)c * 1024 + m0 + mq) = outv;
  }
}

extern "C" void kernel_launch(void* const* d_in, const int* in_sizes, int n_in,
                              void* d_out, int out_size, void* d_ws, size_t ws_size,
                              hipStream_t stream) {
  const float* x    = (const float*)d_in[0];
  const float* w_q  = (const float*)d_in[1];
  const float* b_q  = (const float*)d_in[2];
  const float* w_k  = (const float*)d_in[3];
  const float* b_k  = (const float*)d_in[4];
  const float* w_v  = (const float*)d_in[5];
  const float* b_v  = (const float*)d_in[6];
  const float* w_o  = (const float*)d_in[7];
  const float* b_o  = (const float*)d_in[8];
  const float* dw_w = (const float*)d_in[9];
  const float* dw_b = (const float*)d_in[10];
  const float* ln_g = (const float*)d_in[11];
  const float* ln_b = (const float*)d_in[12];
  const float* off_w= (const float*)d_in[13];
  const float* rpe  = (const float*)d_in[14];

  // Outputs are FLOAT32 (reference returns f32 arrays).
  float* out_y   = (float*)d_out;            // [4,512,32,32]   (2097152 f32)
  float* out_pos = out_y + 2097152;          // [4,4,32,32,2]   (32768 f32)
  float* out_ref = out_pos + 32768;          // [4,4,32,32,2]   (32768 f32)

  // workspace (~16.1 MB): pos f32, then bf16 buffers.
  float* pos_ws = (float*)d_ws;              // 32768 f32
  bf16*  q_ws   = (bf16*)(pos_ws + 32768);   // 2097152 bf16
  bf16*  xs_ws  = q_ws + 2097152;            // 2097152 (reused as ao)
  bf16*  k_ws   = xs_ws + 2097152;           // 2097152
  bf16*  v_ws   = k_ws + 2097152;            // 2097152
  bf16*  ao_ws  = xs_ws;                     // xs dead after k/v gemm

  gemm_kernel<true, bf16, 1><<<dim3(16, 8, 4), 256, 0, stream>>>(
      w_q, b_q, nullptr, nullptr, x, q_ws, (bf16*)nullptr);
  offset_kernel<<<dim3(16, 32), 1024, 0, stream>>>(q_ws, dw_w, dw_b, ln_g, ln_b, off_w,
                                                   pos_ws, out_pos, out_ref);
  sample_kernel<<<dim3(16, 128), 256, 0, stream>>>(x, pos_ws, xs_ws);
  gemm_kernel<false, bf16, 2><<<dim3(16, 8, 4), 256, 0, stream>>>(
      w_k, b_k, w_v, b_v, xs_ws, k_ws, v_ws);
  attn_kernel<<<dim3(16, 32), 512, 0, stream>>>(q_ws, k_ws, v_ws, pos_ws, rpe, ao_ws);
  gemm_kernel<false, float, 1><<<dim3(16, 8, 4), 256, 0, stream>>>(
      w_o, b_o, nullptr, nullptr, ao_ws, out_y, (float*)nullptr);
}